// Round 2
// 5333.103 us; speedup vs baseline: 1.2153x; 1.2153x over previous
//
#include <hip/hip_runtime.h>
#include <hip/hip_bf16.h>

// LSTM N=64, T=512, D=1024, H=1024 — persistent-kernel round (compile-fixed).
// Baseline 6481 us = 512 serial lstm_step launches; ~12.6 us/step vs ~3 us of work
// => launch/drain bound. This round: ONE cooperative persistent kernel, flag barrier per
// (t, batch-group), L2-bypass (sc0 sc1) h exchange (no cache-wide fences -> Wt stays hot
// in L2), c in registers, x pre-converted to bf16 (T,N,D).
//
// ws layout: Wt 16MB | xb 64MB | hb 2x128KB | flags 512KB  (~81MB)

#define T_T 512
#define KTOT 2048

typedef short bf16x8 __attribute__((ext_vector_type(8)));   // 8 bf16 (4 VGPRs)
typedef float f32x4 __attribute__((ext_vector_type(4)));
typedef unsigned u32x4 __attribute__((ext_vector_type(4))); // asm-friendly 128-bit

union B8U { u32x4 u; bf16x8 v; };
union P4 { __hip_bfloat16 h[4]; uint2 u; };

// ---- Wt[a_col][k] = bf16([Wx;Wh][k][a_col]), 4096 x 2048 (unchanged, proven) ----
__global__ __launch_bounds__(256) void prep_weights(const float* __restrict__ Wx,
                                                    const float* __restrict__ Wh,
                                                    __hip_bfloat16* __restrict__ Wt) {
  __shared__ float tile[64][65];
  int kb = blockIdx.x & 31;
  int cb = blockIdx.x >> 5;
  int k0 = kb << 6, c0 = cb << 6;
  const float* W = (k0 < 1024) ? Wx : Wh;
  int kr0 = k0 & 1023;
  int tid = threadIdx.x;
  int f4 = tid & 15;
  int i0 = tid >> 4;
  for (int p = 0; p < 4; ++p) {
    int i = i0 + (p << 4);
    float4 v = *(const float4*)(W + (size_t)(kr0 + i) * 4096 + c0 + (f4 << 2));
    tile[(f4 << 2) + 0][i] = v.x;
    tile[(f4 << 2) + 1][i] = v.y;
    tile[(f4 << 2) + 2][i] = v.z;
    tile[(f4 << 2) + 3][i] = v.w;
  }
  __syncthreads();
  for (int p = 0; p < 16; ++p) {
    int idx = (p << 8) + tid;
    int kl = idx & 63, cl = idx >> 6;
    Wt[(size_t)(c0 + cl) * KTOT + k0 + kl] = __float2bfloat16(tile[cl][kl]);
  }
}

// ---- x (64,512,1024) f32 -> xb (512,64,1024) bf16 ----
__global__ __launch_bounds__(256) void prep_xb(const float* __restrict__ x,
                                               __hip_bfloat16* __restrict__ xb) {
  int b = blockIdx.x;            // 32768 = 512*64
  int n = b & 63, t = b >> 6;
  const float4* src = (const float4*)(x + ((size_t)n * T_T + t) * 1024);
  __hip_bfloat16* dst = xb + ((size_t)t * 64 + n) * 1024;
  float4 v = src[threadIdx.x];
  P4 pk;
  pk.h[0] = __float2bfloat16(v.x);
  pk.h[1] = __float2bfloat16(v.y);
  pk.h[2] = __float2bfloat16(v.z);
  pk.h[3] = __float2bfloat16(v.w);
  *(uint2*)(dst + (threadIdx.x << 2)) = pk.u;
}

// ---- h0 -> bf16 into hb[0] ----
__global__ __launch_bounds__(256) void prep_state(const float* __restrict__ h0,
                                                  __hip_bfloat16* __restrict__ hb) {
  int i = blockIdx.x * 256 + threadIdx.x;   // 65536
  hb[i] = __float2bfloat16(h0[i]);
}

// ---- persistent LSTM: all 512 steps in one cooperative kernel ----
__global__ __launch_bounds__(256) void lstm_persist(
    const __hip_bfloat16* __restrict__ xb,   // (512,64,1024)
    const float* __restrict__ bias,
    const __hip_bfloat16* __restrict__ Wt,   // (4096,2048) gate-major rows
    __hip_bfloat16* hb,                      // [2][64*1024] double buffer
    float* __restrict__ out,                 // (64,512,1024)
    unsigned* flags)                         // [512][4][64]
{
  __shared__ __align__(16) __hip_bfloat16 Alds[16][1032]; // pad 8 -> <=2-way bank conflict
  __shared__ float gtile[4][16][17];
  __shared__ __align__(16) __hip_bfloat16 hrow[16][16];

  const int tid  = threadIdx.x;
  const int cgrp = blockIdx.x & 63;   // h-cols [16*cgrp, +16)
  const int bg   = blockIdx.x >> 6;   // batch rows [16*bg, +16) — independent chain per bg
  const int rows0 = bg << 4;
  const int lane = tid & 63;
  const int wv   = tid >> 6;          // wave = gate
  const int mcol = lane & 15;
  const int q    = lane >> 4;
  const size_t wrow = ((size_t)(wv << 10) + (cgrp << 4) + mcol) * (size_t)KTOT;

  // epilogue role: thread -> (row er, h-col ej); c stays in this thread's register.
  const int er = tid >> 4, ej = tid & 15;
  const int hcol = (cgrp << 4) + ej;
  const int rg = rows0 + er;
  const float b_i = bias[hcol];
  const float b_f = bias[1024 + hcol];
  const float b_o = bias[2048 + hcol];
  const float b_g = bias[3072 + hcol];
  float creg = 0.f;
  int poison = 0;

  for (int t = 0; t < T_T; ++t) {
    // ---- stage xb_t (cached loads; xb is read-only) ----
    {
      const u32x4* src = (const u32x4*)(xb + ((size_t)t * 64 + rows0) * 1024);
      #pragma unroll
      for (int p = 0; p < 8; ++p) {
        int idx = (p << 8) + tid;
        int r = idx >> 7, c8 = idx & 127;
        u32x4 v = src[(size_t)r * 128 + c8];
        *(u32x4*)&Alds[r][c8 << 3] = v;
      }
    }
    __syncthreads();
    // ---- x-part GEMM (no h dependency — overlaps barrier latency of other WGs) ----
    f32x4 acc = {0.f, 0.f, 0.f, 0.f};
    #pragma unroll 4
    for (int kk = 0; kk < 32; ++kk) {
      B8U a, b;
      a.u = *(const u32x4*)&Alds[mcol][(kk << 5) + (q << 3)];
      b.u = *(const u32x4*)(Wt + wrow + (kk << 5) + (q << 3));
      acc = __builtin_amdgcn_mfma_f32_16x16x32_bf16(a.v, b.v, acc, 0, 0, 0);
    }
    // ---- wait for h_{t-1} from this bg's 64 producers ----
    if (t > 0) {
      unsigned* fp = flags + (((unsigned)(t - 1) << 8) | ((unsigned)bg << 6)) + lane;
      int spun = 0;
      while (!poison) {
        unsigned v = __hip_atomic_load(fp, __ATOMIC_RELAXED, __HIP_MEMORY_SCOPE_AGENT);
        if (__all(v != 0)) break;
        __builtin_amdgcn_s_sleep(1);
        if (++spun > (1 << 24)) poison = 1;   // bail -> wrong answer, not a hang
      }
    }
    __syncthreads();   // all waves done with Alds(x) and past the wait
    // ---- stage h_{t-1}: L2-bypass loads (other XCDs wrote it, our L2 may be stale) ----
    {
      const __hip_bfloat16* hsrc = hb + ((size_t)(t & 1) << 16);
      const char* base = (const char*)(hsrc + (size_t)rows0 * 1024)
                       + ((tid & 127) << 4) + ((tid >> 7) << 11);
      const char* p0 = base;          const char* p1 = base + 4096;
      const char* p2 = base + 8192;   const char* p3 = base + 12288;
      const char* p4 = base + 16384;  const char* p5 = base + 20480;
      const char* p6 = base + 24576;  const char* p7 = base + 28672;
      u32x4 d0, d1, d2, d3, d4, d5, d6, d7;
      asm volatile(
        "global_load_dwordx4 %0, %8, off sc0 sc1\n\t"
        "global_load_dwordx4 %1, %9, off sc0 sc1\n\t"
        "global_load_dwordx4 %2, %10, off sc0 sc1\n\t"
        "global_load_dwordx4 %3, %11, off sc0 sc1\n\t"
        "global_load_dwordx4 %4, %12, off sc0 sc1\n\t"
        "global_load_dwordx4 %5, %13, off sc0 sc1\n\t"
        "global_load_dwordx4 %6, %14, off sc0 sc1\n\t"
        "global_load_dwordx4 %7, %15, off sc0 sc1\n\t"
        "s_waitcnt vmcnt(0)"
        : "=&v"(d0), "=&v"(d1), "=&v"(d2), "=&v"(d3),
          "=&v"(d4), "=&v"(d5), "=&v"(d6), "=&v"(d7)
        : "v"(p0), "v"(p1), "v"(p2), "v"(p3),
          "v"(p4), "v"(p5), "v"(p6), "v"(p7)
        : "memory");
      int hr = tid >> 7, c8 = tid & 127;
      *(u32x4*)&Alds[hr +  0][c8 << 3] = d0;
      *(u32x4*)&Alds[hr +  2][c8 << 3] = d1;
      *(u32x4*)&Alds[hr +  4][c8 << 3] = d2;
      *(u32x4*)&Alds[hr +  6][c8 << 3] = d3;
      *(u32x4*)&Alds[hr +  8][c8 << 3] = d4;
      *(u32x4*)&Alds[hr + 10][c8 << 3] = d5;
      *(u32x4*)&Alds[hr + 12][c8 << 3] = d6;
      *(u32x4*)&Alds[hr + 14][c8 << 3] = d7;
    }
    __syncthreads();
    // ---- h-part GEMM (K 1024..2047) ----
    #pragma unroll 4
    for (int kk = 0; kk < 32; ++kk) {
      B8U a, b;
      a.u = *(const u32x4*)&Alds[mcol][(kk << 5) + (q << 3)];
      b.u = *(const u32x4*)(Wt + wrow + 1024 + (kk << 5) + (q << 3));
      acc = __builtin_amdgcn_mfma_f32_16x16x32_bf16(a.v, b.v, acc, 0, 0, 0);
    }
    #pragma unroll
    for (int i = 0; i < 4; ++i)
      gtile[wv][(q << 2) + i][mcol] = acc[i];
    __syncthreads();
    // ---- epilogue: gates, c in register, write out + h_t ----
    {
      float av_i = gtile[0][er][ej] + b_i;
      float av_f = gtile[1][er][ej] + b_f;
      float av_o = gtile[2][er][ej] + b_o;
      float av_g = gtile[3][er][ej] + b_g;
      float iv = 1.f / (1.f + expf(-av_i));
      float fv = 1.f / (1.f + expf(-av_f));
      float ov = 1.f / (1.f + expf(-av_o));
      float gv = tanhf(av_g);
      float cn = fv * creg + iv * gv;
      creg = cn;
      float hv = ov * tanhf(cn);
      out[((size_t)rg * T_T + t) * 1024 + hcol] = hv;   // normal store (write-only)
      hrow[er][ej] = __float2bfloat16(hv);
    }
    __syncthreads();
    if (tid < 32) {   // 16x16 bf16 tile = 32 x dwordx4, L2-bypass stores
      u32x4 v = *(const u32x4*)&hrow[tid >> 1][(tid & 1) << 3];
      __hip_bfloat16* hd = hb + ((size_t)((t + 1) & 1) << 16)
                         + (size_t)(rows0 + (tid >> 1)) * 1024
                         + (cgrp << 4) + ((tid & 1) << 3);
      asm volatile("global_store_dwordx4 %0, %1, off sc0 sc1"
                   :: "v"(hd), "v"(v) : "memory");
    }
    asm volatile("s_waitcnt vmcnt(0)" ::: "memory");  // h (and out) stores acked at L3
    __syncthreads();
    if (tid == 0)
      __hip_atomic_store(flags + (((unsigned)t << 8) | ((unsigned)bg << 6)) + cgrp, 1u,
                         __ATOMIC_RELAXED, __HIP_MEMORY_SCOPE_AGENT);
  }
}

extern "C" void kernel_launch(void* const* d_in, const int* in_sizes, int n_in,
                              void* d_out, int out_size, void* d_ws, size_t ws_size,
                              hipStream_t stream) {
  const float* x    = (const float*)d_in[0];   // (64,512,1024)
  const float* h0   = (const float*)d_in[1];   // (64,1024)
  const float* Wx   = (const float*)d_in[2];   // (1024,4096)
  const float* Wh   = (const float*)d_in[3];   // (1024,4096)
  const float* bias = (const float*)d_in[4];   // (4096)
  float* out = (float*)d_out;

  char* ws = (char*)d_ws;
  __hip_bfloat16* Wt  = (__hip_bfloat16*)ws;                                 // 16 MiB
  __hip_bfloat16* xb  = (__hip_bfloat16*)(ws + ((size_t)16 << 20));          // 64 MiB
  __hip_bfloat16* hbf = (__hip_bfloat16*)(ws + ((size_t)80 << 20));          // 256 KiB
  unsigned* flags     = (unsigned*)(ws + ((size_t)80 << 20) + (1u << 18));   // 512 KiB

  hipLaunchKernelGGL(prep_weights, dim3(2048), dim3(256), 0, stream, Wx, Wh, Wt);
  hipLaunchKernelGGL(prep_xb, dim3(32768), dim3(256), 0, stream, x, xb);
  hipLaunchKernelGGL(prep_state, dim3(256), dim3(256), 0, stream, h0, hbf);
  (void)hipMemsetAsync(flags, 0, (size_t)512 * 4 * 64 * sizeof(unsigned), stream);

  void* kargs[6];
  kargs[0] = (void*)&xb;
  kargs[1] = (void*)&bias;
  kargs[2] = (void*)&Wt;
  kargs[3] = (void*)&hbf;
  kargs[4] = (void*)&out;
  kargs[5] = (void*)&flags;
  (void)hipLaunchCooperativeKernel(lstm_persist, dim3(256), dim3(256), kargs, 0, stream);
}